// Round 1
// baseline (727.607 us; speedup 1.0000x reference)
//
#include <hip/hip_runtime.h>
#include <hip/hip_bf16.h>

typedef __bf16 bf16x8 __attribute__((ext_vector_type(8)));
typedef float f32x4 __attribute__((ext_vector_type(4)));
typedef unsigned short ushort_t;
typedef unsigned int uint_t;

#define HN 16
#define LSEQ 256
#define DD 1024
#define BB 4
#define SS 4096
#define MROWS (BB * SS) /* 16384 */
#define BHN (BB * HN)   /* 64 */

__device__ __forceinline__ ushort_t f2bf(float f) {
  uint_t u = __builtin_bit_cast(uint_t, f);
  u += 0x7fffu + ((u >> 16) & 1u); // RNE
  return (ushort_t)(u >> 16);
}

// ---------- weight transpose: W fp32 [K][N] -> WT bf16 [N][K] ----------
__global__ __launch_bounds__(256) void transpose_w(const float* __restrict__ W,
                                                   ushort_t* __restrict__ WT) {
  __shared__ float tile[32][33];
  const int tx = threadIdx.x, ty = threadIdx.y;
  const int bn = blockIdx.x * 32, bk = blockIdx.y * 32;
#pragma unroll
  for (int j = 0; j < 32; j += 8)
    tile[ty + j][tx] = W[(long)(bk + ty + j) * DD + bn + tx];
  __syncthreads();
#pragma unroll
  for (int j = 0; j < 32; j += 8)
    WT[(long)(bn + ty + j) * DD + bk + tx] = f2bf(tile[tx][ty + j]);
}

// ---------- vh transpose per (b,h): [256][1024] -> [1024][256] bf16 ----------
__global__ __launch_bounds__(256) void transpose_v(const ushort_t* __restrict__ vh,
                                                   ushort_t* __restrict__ vhT) {
  __shared__ ushort_t tile[32][33];
  const int tx = threadIdx.x, ty = threadIdx.y;
  const long zo = (long)blockIdx.z * (LSEQ * DD);
  const ushort_t* src = vh + zo;
  ushort_t* dst = vhT + zo;
  const int bd = blockIdx.x * 32; // d
  const int bl = blockIdx.y * 32; // l
#pragma unroll
  for (int j = 0; j < 32; j += 8)
    tile[ty + j][tx] = src[(long)(bl + ty + j) * DD + bd + tx];
  __syncthreads();
#pragma unroll
  for (int j = 0; j < 32; j += 8)
    dst[(long)(bd + ty + j) * LSEQ + bl + tx] = tile[tx][ty + j];
}

// ---------- scale + mask + softmax: S fp32 [16384][256] -> att bf16 ----------
__global__ __launch_bounds__(256) void softmax_mask(const float* __restrict__ Sc,
                                                    const int* __restrict__ mask,
                                                    ushort_t* __restrict__ att) {
  const int wid = threadIdx.x >> 6, lane = threadIdx.x & 63;
  const int g = blockIdx.x * 4 + wid; // global row: bh*256 + l
  const int bh = g >> 8, l = g & 255;
  const int b = bh >> 4;
  const float4 sv = *(const float4*)&Sc[(long)g * 256 + lane * 4];
  const int4 mv = *(const int4*)&mask[((long)b * 256 + l) * 256 + lane * 4];
  float s[4];
  s[0] = (mv.x == 0) ? 1e-9f : sv.x * 0.03125f;
  s[1] = (mv.y == 0) ? 1e-9f : sv.y * 0.03125f;
  s[2] = (mv.z == 0) ? 1e-9f : sv.z * 0.03125f;
  s[3] = (mv.w == 0) ? 1e-9f : sv.w * 0.03125f;
  float mx = fmaxf(fmaxf(s[0], s[1]), fmaxf(s[2], s[3]));
#pragma unroll
  for (int off = 32; off; off >>= 1) mx = fmaxf(mx, __shfl_xor(mx, off));
  float e[4], sum = 0.f;
#pragma unroll
  for (int i = 0; i < 4; ++i) {
    e[i] = __expf(s[i] - mx);
    sum += e[i];
  }
#pragma unroll
  for (int off = 32; off; off >>= 1) sum += __shfl_xor(sum, off);
  const float inv = 1.0f / sum;
  ushort4 o;
  o.x = f2bf(e[0] * inv);
  o.y = f2bf(e[1] * inv);
  o.z = f2bf(e[2] * inv);
  o.w = f2bf(e[3] * inv);
  *(ushort4*)&att[(long)g * 256 + lane * 4] = o;
}

// ---------- generic TN GEMM: C[M][N] = A[M][K] * Bt[N][K]^T ----------
// AMODE: 0 = A fp32 (convert on stage), 1 = A bf16
// SMODE: 0 = fp32 plain store (ldC), 1 = bf16 proj-permute store, 2 = bf16 pv-permute store
template <int AMODE, int SMODE>
__global__ __launch_bounds__(256, 2) void gemm_tn(const void* __restrict__ Ap,
                                                  const ushort_t* __restrict__ Btp,
                                                  void* __restrict__ Cp, int K, int ldA,
                                                  int ldB, int ldC, long batchA,
                                                  long batchB, long batchC) {
  // LDS tiles: [128 rows][40] bf16 (row pad 32->40 keeps b128 reads 16B-aligned, ~2-way banks)
  __shared__ ushort_t sA[2 * 128 * 40];
  __shared__ ushort_t sB[2 * 128 * 40];

  const int z = blockIdx.z;
  const int rowBase = blockIdx.y * 128;
  const int colBase = blockIdx.x * 128;

  const int t = threadIdx.x;
  const int lane = t & 63;
  const int wid = t >> 6;
  const int wr = (wid >> 1) * 64;
  const int wc = (wid & 1) * 64;
  const int fr = lane & 15;
  const int fk = (lane >> 4) * 8;

  const int srow = t >> 1;        // 0..127
  const int skh = (t & 1) << 4;   // 0 or 16

  const float* Af = (const float*)Ap + batchA * z;
  const ushort_t* Ab = (const ushort_t*)Ap + batchA * z;
  const ushort_t* Bt = Btp + batchB * z;

  const float* agf = Af + (long)(rowBase + srow) * ldA + skh;
  const ushort_t* agb = Ab + (long)(rowBase + srow) * ldA + skh;
  const ushort_t* bg = Bt + (long)(colBase + srow) * ldB + skh;

  f32x4 acc[4][4];
#pragma unroll
  for (int m = 0; m < 4; ++m)
#pragma unroll
    for (int n = 0; n < 4; ++n) acc[m][n] = (f32x4){0.f, 0.f, 0.f, 0.f};

  const int NT = K >> 5;

  float4 ra[4];
  uint4 rab[2];
  uint4 rb[2];

  auto G2R = [&](int kt) {
    const long ko = (long)kt * 32;
    if constexpr (AMODE == 0) {
      const float* p = agf + ko;
      ra[0] = *(const float4*)(p + 0);
      ra[1] = *(const float4*)(p + 4);
      ra[2] = *(const float4*)(p + 8);
      ra[3] = *(const float4*)(p + 12);
    } else {
      const ushort_t* p = agb + ko;
      rab[0] = *(const uint4*)(p + 0);
      rab[1] = *(const uint4*)(p + 8);
    }
    const ushort_t* qp = bg + ko;
    rb[0] = *(const uint4*)(qp + 0);
    rb[1] = *(const uint4*)(qp + 8);
  };

  auto R2S = [&](int buf) {
    ushort_t* da = &sA[buf * 5120 + srow * 40 + skh];
    if constexpr (AMODE == 0) {
      uint_t w[8];
#pragma unroll
      for (int i = 0; i < 4; ++i) {
        const float4 vv = ra[i];
        w[i * 2 + 0] = (uint_t)f2bf(vv.x) | ((uint_t)f2bf(vv.y) << 16);
        w[i * 2 + 1] = (uint_t)f2bf(vv.z) | ((uint_t)f2bf(vv.w) << 16);
      }
      *(uint4*)da = make_uint4(w[0], w[1], w[2], w[3]);
      *(uint4*)(da + 8) = make_uint4(w[4], w[5], w[6], w[7]);
    } else {
      *(uint4*)da = rab[0];
      *(uint4*)(da + 8) = rab[1];
    }
    ushort_t* db = &sB[buf * 5120 + srow * 40 + skh];
    *(uint4*)db = rb[0];
    *(uint4*)(db + 8) = rb[1];
  };

  G2R(0);
  R2S(0);
  __syncthreads();

  for (int kt = 0; kt < NT; ++kt) {
    const int cur = kt & 1;
    if (kt + 1 < NT) G2R(kt + 1);

    bf16x8 af[4], bfv[4];
    const ushort_t* baseA = &sA[cur * 5120 + fk];
    const ushort_t* baseB = &sB[cur * 5120 + fk];
#pragma unroll
    for (int m = 0; m < 4; ++m) af[m] = *(const bf16x8*)(baseA + (wr + m * 16 + fr) * 40);
#pragma unroll
    for (int n = 0; n < 4; ++n) bfv[n] = *(const bf16x8*)(baseB + (wc + n * 16 + fr) * 40);

#pragma unroll
    for (int m = 0; m < 4; ++m)
#pragma unroll
      for (int n = 0; n < 4; ++n)
        acc[m][n] = __builtin_amdgcn_mfma_f32_16x16x32_bf16(af[m], bfv[n], acc[m][n], 0, 0, 0);

    if (kt + 1 < NT) R2S(cur ^ 1);
    __syncthreads();
  }

  const int rq = (lane >> 4) * 4;
#pragma unroll
  for (int m = 0; m < 4; ++m) {
#pragma unroll
    for (int n = 0; n < 4; ++n) {
#pragma unroll
      for (int r = 0; r < 4; ++r) {
        const int grow = rowBase + wr + m * 16 + rq + r;
        const int gcol = colBase + wc + n * 16 + fr;
        if constexpr (SMODE == 0) {
          float* Cf = (float*)Cp + batchC * z;
          Cf[(long)grow * ldC + gcol] = acc[m][n][r];
        } else if constexpr (SMODE == 1) {
          // input row grow = b*4096 + s, s = l*16+h -> out row (b*16+h)*256+l
          ushort_t* Cb = (ushort_t*)Cp;
          const int b = grow >> 12;
          const int s = grow & 4095;
          const int orow = ((b << 4) + (s & 15)) * 256 + (s >> 4);
          Cb[(long)orow * 1024 + gcol] = f2bf(acc[m][n][r]);
        } else {
          // grow = l, z = b*16+h -> out row b*4096 + l*16 + h
          ushort_t* Cb = (ushort_t*)Cp;
          const int b = z >> 4;
          const int h = z & 15;
          const int orow = (b << 12) + grow * 16 + h;
          Cb[(long)orow * 1024 + gcol] = f2bf(acc[m][n][r]);
        }
      }
    }
  }
}

extern "C" void kernel_launch(void* const* d_in, const int* in_sizes, int n_in,
                              void* d_out, int out_size, void* d_ws, size_t ws_size,
                              hipStream_t stream) {
  const float* q = (const float*)d_in[0];
  const float* k = (const float*)d_in[1];
  const float* v = (const float*)d_in[2];
  const int* mask = (const int*)d_in[3];
  const float* Wq = (const float*)d_in[4];
  const float* Wk = (const float*)d_in[5];
  const float* Wv = (const float*)d_in[6];
  const float* Wo = (const float*)d_in[7];
  float* out = (float*)d_out;

  // workspace layout (bytes total ~192 MiB)
  ushort_t* WTq = (ushort_t*)d_ws;
  ushort_t* WTk = WTq + (size_t)1024 * 1024;
  ushort_t* WTv = WTk + (size_t)1024 * 1024;
  ushort_t* WTo = WTv + (size_t)1024 * 1024;
  ushort_t* qh = WTo + (size_t)1024 * 1024;
  ushort_t* kh = qh + (size_t)MROWS * 1024;
  ushort_t* vh = kh + (size_t)MROWS * 1024;
  ushort_t* vhT = vh + (size_t)MROWS * 1024;
  float* Sc = (float*)(vhT + (size_t)MROWS * 1024);
  ushort_t* att = (ushort_t*)(Sc + (size_t)BHN * 256 * 256);
  ushort_t* x = att + (size_t)BHN * 256 * 256;

  const dim3 tb(32, 8);
  transpose_w<<<dim3(32, 32), tb, 0, stream>>>(Wq, WTq);
  transpose_w<<<dim3(32, 32), tb, 0, stream>>>(Wk, WTk);
  transpose_w<<<dim3(32, 32), tb, 0, stream>>>(Wv, WTv);
  transpose_w<<<dim3(32, 32), tb, 0, stream>>>(Wo, WTo);

  // projections: [16384,1024] = in @ W ; permuted bf16 store into [b][h][l][d]
  gemm_tn<0, 1><<<dim3(8, 128), 256, 0, stream>>>(q, WTq, qh, 1024, 1024, 1024, 1024, 0, 0, 0);
  gemm_tn<0, 1><<<dim3(8, 128), 256, 0, stream>>>(k, WTk, kh, 1024, 1024, 1024, 1024, 0, 0, 0);
  gemm_tn<0, 1><<<dim3(8, 128), 256, 0, stream>>>(v, WTv, vh, 1024, 1024, 1024, 1024, 0, 0, 0);

  transpose_v<<<dim3(32, 8, BHN), tb, 0, stream>>>(vh, vhT);

  // scores: per bh, S[256][256] = qh @ kh^T (raw, fp32)
  gemm_tn<1, 0><<<dim3(2, 2, BHN), 256, 0, stream>>>(qh, kh, Sc, 1024, 1024, 1024, 256,
                                                     (long)256 * 1024, (long)256 * 1024,
                                                     (long)65536);
  // scale + mask + softmax -> att bf16
  softmax_mask<<<4096, 256, 0, stream>>>(Sc, mask, att);

  // PV: per bh, x_bh[256][1024] = att @ vh ; permuted store back to [b][s][d]
  gemm_tn<1, 2><<<dim3(8, 2, BHN), 256, 0, stream>>>(att, vhT, x, 256, 256, 256, 1024,
                                                     (long)65536, (long)262144, 0);

  // out = x @ Wo, fp32
  gemm_tn<1, 0><<<dim3(8, 128), 256, 0, stream>>>(x, WTo, out, 1024, 1024, 1024, 1024, 0, 0, 0);
}

// Round 2
// 323.320 us; speedup vs baseline: 2.2504x; 2.2504x over previous
//
#include <hip/hip_runtime.h>
#include <hip/hip_bf16.h>

typedef __bf16 bf16x8 __attribute__((ext_vector_type(8)));
typedef float f32x4 __attribute__((ext_vector_type(4)));
typedef unsigned short ushort_t;
typedef unsigned int uint_t;

#define HN 16
#define LSEQ 256
#define DD 1024
#define BB 4
#define SS 4096
#define MROWS (BB * SS) /* 16384 */
#define BHN (BB * HN)   /* 64 */

__device__ __forceinline__ ushort_t f2bf(float f) {
  uint_t u = __builtin_bit_cast(uint_t, f);
  u += 0x7fffu + ((u >> 16) & 1u); // RNE
  return (ushort_t)(u >> 16);
}
__device__ __forceinline__ uint_t pk2(float lo, float hi) {
  return (uint_t)f2bf(lo) | ((uint_t)f2bf(hi) << 16);
}

// ---------- fp32 -> bf16 bulk convert (8 elems/thread) ----------
__global__ __launch_bounds__(256) void cvt_bf16(const float4* __restrict__ in,
                                                uint4* __restrict__ out) {
  const long i = (long)blockIdx.x * 256 + threadIdx.x;
  const float4 a = in[i * 2];
  const float4 b = in[i * 2 + 1];
  uint4 o;
  o.x = pk2(a.x, a.y);
  o.y = pk2(a.z, a.w);
  o.z = pk2(b.x, b.y);
  o.w = pk2(b.z, b.w);
  out[i] = o;
}

// ---------- weight transpose: W fp32 [K][N] -> WT bf16 [N][K] ----------
__global__ __launch_bounds__(256) void transpose_w(const float* __restrict__ W,
                                                   ushort_t* __restrict__ WT) {
  __shared__ float tile[32][33];
  const int tx = threadIdx.x, ty = threadIdx.y;
  const int bn = blockIdx.x * 32, bk = blockIdx.y * 32;
#pragma unroll
  for (int j = 0; j < 32; j += 8)
    tile[ty + j][tx] = W[(long)(bk + ty + j) * DD + bn + tx];
  __syncthreads();
#pragma unroll
  for (int j = 0; j < 32; j += 8)
    WT[(long)(bn + ty + j) * DD + bk + tx] = f2bf(tile[tx][ty + j]);
}

// ---------- vh transpose per (b,h): [256][1024] -> [1024][256] bf16 ----------
__global__ __launch_bounds__(256) void transpose_v(const ushort_t* __restrict__ vh,
                                                   ushort_t* __restrict__ vhT) {
  __shared__ ushort_t tile[32][33];
  const int tx = threadIdx.x, ty = threadIdx.y;
  const long zo = (long)blockIdx.z * (LSEQ * DD);
  const ushort_t* src = vh + zo;
  ushort_t* dst = vhT + zo;
  const int bd = blockIdx.x * 32; // d
  const int bl = blockIdx.y * 32; // l
#pragma unroll
  for (int j = 0; j < 32; j += 8)
    tile[ty + j][tx] = src[(long)(bl + ty + j) * DD + bd + tx];
  __syncthreads();
#pragma unroll
  for (int j = 0; j < 32; j += 8)
    dst[(long)(bd + ty + j) * LSEQ + bl + tx] = tile[tx][ty + j];
}

// ---------- scale + mask + softmax: S fp32 [16384][256] -> att bf16 ----------
__global__ __launch_bounds__(256) void softmax_mask(const float* __restrict__ Sc,
                                                    const int* __restrict__ mask,
                                                    ushort_t* __restrict__ att) {
  const int wid = threadIdx.x >> 6, lane = threadIdx.x & 63;
  const int g = blockIdx.x * 4 + wid; // global row: bh*256 + l
  const int bh = g >> 8, l = g & 255;
  const int b = bh >> 4;
  const float4 sv = *(const float4*)&Sc[(long)g * 256 + lane * 4];
  const int4 mv = *(const int4*)&mask[((long)b * 256 + l) * 256 + lane * 4];
  float s[4];
  s[0] = (mv.x == 0) ? 1e-9f : sv.x * 0.03125f;
  s[1] = (mv.y == 0) ? 1e-9f : sv.y * 0.03125f;
  s[2] = (mv.z == 0) ? 1e-9f : sv.z * 0.03125f;
  s[3] = (mv.w == 0) ? 1e-9f : sv.w * 0.03125f;
  float mx = fmaxf(fmaxf(s[0], s[1]), fmaxf(s[2], s[3]));
#pragma unroll
  for (int off = 32; off; off >>= 1) mx = fmaxf(mx, __shfl_xor(mx, off));
  float e[4], sum = 0.f;
#pragma unroll
  for (int i = 0; i < 4; ++i) {
    e[i] = __expf(s[i] - mx);
    sum += e[i];
  }
#pragma unroll
  for (int off = 32; off; off >>= 1) sum += __shfl_xor(sum, off);
  const float inv = 1.0f / sum;
  ushort4 o;
  o.x = f2bf(e[0] * inv);
  o.y = f2bf(e[1] * inv);
  o.z = f2bf(e[2] * inv);
  o.w = f2bf(e[3] * inv);
  *(ushort4*)&att[(long)g * 256 + lane * 4] = o;
}

// ---------- TN GEMM, bf16 A and Bt, global_load_lds staged ----------
// C[M][N] = A[M][K] * Bt[N][K]^T
// SMODE: 0 = fp32 plain store (ldC), 1 = bf16 proj-permute, 2 = bf16 pv-permute
// SWZ: bijective XCD-aware remap of a 1D grid (nwg % 8 == 0 required)
template <int SMODE, bool SWZ>
__global__ __launch_bounds__(256, 2) void gemm_tn(const ushort_t* __restrict__ Ab,
                                                  const ushort_t* __restrict__ Btp,
                                                  void* __restrict__ Cp, int K, int ldA,
                                                  int ldB, int ldC, int nbx, long batchA,
                                                  long batchB, long batchC) {
  __shared__ ushort_t smem[16384]; // 32 KB: staging 2x(A,B) 128x32; epilogue 128x128
  ushort_t* sA = smem;        // 2 bufs x 4096 elems
  ushort_t* sB = smem + 8192; // 2 bufs x 4096 elems

  int bx, by;
  if constexpr (SWZ) {
    const int orig = blockIdx.x;
    const int lin = (orig & 7) * ((int)gridDim.x >> 3) + (orig >> 3);
    bx = lin % nbx;
    by = lin / nbx;
  } else {
    bx = blockIdx.x;
    by = blockIdx.y;
  }
  const int z = blockIdx.z;
  const int rowBase = by * 128;
  const int colBase = bx * 128;

  const int t = threadIdx.x;
  const int lane = t & 63;
  const int wid = t >> 6;
  const int wr = (wid >> 1) * 64;
  const int wc = (wid & 1) * 64;
  const int fr = lane & 15;
  const int fk = (lane >> 4) * 8;

  const ushort_t* Atile = Ab + batchA * z + (long)rowBase * ldA;
  const ushort_t* Btile = Btp + batchB * z + (long)colBase * ldB;

  f32x4 acc[4][4];
#pragma unroll
  for (int m = 0; m < 4; ++m)
#pragma unroll
    for (int n = 0; n < 4; ++n) acc[m][n] = (f32x4){0.f, 0.f, 0.f, 0.f};

  const int NT = K >> 5;

  // stage 128x32 bf16 tiles of A and B into buf via global_load_lds (16B/lane)
  auto stageAB = [&](int buf, int kt) {
    const long ko = (long)kt * 32;
#pragma unroll
    for (int i = 0; i < 2; ++i) {
      const int c = i * 256 + t;          // 16B chunk id: row = c>>2, colpart = (c&3)*8
      const int cw = i * 256 + (t & 192); // wave-uniform chunk base
      __builtin_amdgcn_global_load_lds(
          (const __attribute__((address_space(1))) void*)(Atile + (long)(c >> 2) * ldA + ko +
                                                          (c & 3) * 8),
          (__attribute__((address_space(3))) void*)(sA + buf * 4096 + cw * 8), 16, 0, 0);
      __builtin_amdgcn_global_load_lds(
          (const __attribute__((address_space(1))) void*)(Btile + (long)(c >> 2) * ldB + ko +
                                                          (c & 3) * 8),
          (__attribute__((address_space(3))) void*)(sB + buf * 4096 + cw * 8), 16, 0, 0);
    }
  };

  stageAB(0, 0);
  __syncthreads();

  int cur = 0;
  for (int kt = 0; kt < NT; ++kt) {
    if (kt + 1 < NT) stageAB(cur ^ 1, kt + 1);

    bf16x8 af[4], bfv[4];
    const ushort_t* baseA = sA + cur * 4096 + fk;
    const ushort_t* baseB = sB + cur * 4096 + fk;
#pragma unroll
    for (int m = 0; m < 4; ++m) af[m] = *(const bf16x8*)(baseA + (wr + m * 16 + fr) * 32);
#pragma unroll
    for (int n = 0; n < 4; ++n) bfv[n] = *(const bf16x8*)(baseB + (wc + n * 16 + fr) * 32);

#pragma unroll
    for (int m = 0; m < 4; ++m)
#pragma unroll
      for (int n = 0; n < 4; ++n)
        acc[m][n] = __builtin_amdgcn_mfma_f32_16x16x32_bf16(af[m], bfv[n], acc[m][n], 0, 0, 0);

    __syncthreads(); // drains vmcnt(0)+lgkmcnt(0): next buf staged, reads done
    cur ^= 1;
  }

  const int rq = (lane >> 4) * 4;
  if constexpr (SMODE == 0) {
    float* Cf = (float*)Cp + batchC * z;
#pragma unroll
    for (int m = 0; m < 4; ++m)
#pragma unroll
      for (int n = 0; n < 4; ++n)
#pragma unroll
        for (int r = 0; r < 4; ++r)
          Cf[(long)(rowBase + wr + m * 16 + rq + r) * ldC + colBase + wc + n * 16 + fr] =
              acc[m][n][r];
  } else {
    // stage C tile to LDS as [128][128] bf16, then full-line permuted stores
#pragma unroll
    for (int m = 0; m < 4; ++m)
#pragma unroll
      for (int n = 0; n < 4; ++n)
#pragma unroll
        for (int r = 0; r < 4; ++r)
          smem[(wr + m * 16 + rq + r) * 128 + wc + n * 16 + fr] = f2bf(acc[m][n][r]);
    __syncthreads();
    ushort_t* Cb = (ushort_t*)Cp;
    const int c8 = (lane & 15) * 8;
#pragma unroll
    for (int i = 0; i < 8; ++i) {
      const int row = i * 16 + wid * 4 + (lane >> 4);
      const uint4 val = *(const uint4*)(smem + row * 128 + c8);
      int orow;
      if constexpr (SMODE == 1) {
        const int grow = rowBase + row; // = b*4096 + s, s = l*16+h
        const int b = grow >> 12;
        const int s = grow & 4095;
        orow = ((b << 4) + (s & 15)) * 256 + (s >> 4); // (b*16+h)*256 + l
      } else {
        const int l = rowBase + row;
        orow = ((z >> 4) << 12) + l * 16 + (z & 15); // b*4096 + l*16 + h
      }
      *(uint4*)(Cb + (long)orow * 1024 + colBase + c8) = val;
    }
  }
}

extern "C" void kernel_launch(void* const* d_in, const int* in_sizes, int n_in,
                              void* d_out, int out_size, void* d_ws, size_t ws_size,
                              hipStream_t stream) {
  const float* q = (const float*)d_in[0];
  const float* k = (const float*)d_in[1];
  const float* v = (const float*)d_in[2];
  const int* mask = (const int*)d_in[3];
  const float* Wq = (const float*)d_in[4];
  const float* Wk = (const float*)d_in[5];
  const float* Wv = (const float*)d_in[6];
  const float* Wo = (const float*)d_in[7];
  float* out = (float*)d_out;

  // workspace layout (peak 168 MiB), with aliasing:
  char* ws = (char*)d_ws;
  const size_t MB = 1024 * 1024;
  ushort_t* WTq = (ushort_t*)(ws + 0 * MB);
  ushort_t* WTk = (ushort_t*)(ws + 2 * MB);
  ushort_t* WTv = (ushort_t*)(ws + 4 * MB);
  ushort_t* WTo = (ushort_t*)(ws + 6 * MB);
  ushort_t* buf0 = (ushort_t*)(ws + 8 * MB);  // qb/kb/vb (32MB), later Sc (16MB)
  ushort_t* qh = (ushort_t*)(ws + 40 * MB);   // later att (8MB)
  ushort_t* kh = (ushort_t*)(ws + 72 * MB);   // later x (32MB)
  ushort_t* vh = (ushort_t*)(ws + 104 * MB);
  ushort_t* vhT = (ushort_t*)(ws + 136 * MB);
  float* Sc = (float*)buf0;
  ushort_t* att = qh;
  ushort_t* x = kh;

  const dim3 tb(32, 8);
  transpose_w<<<dim3(32, 32), tb, 0, stream>>>(Wq, WTq);
  transpose_w<<<dim3(32, 32), tb, 0, stream>>>(Wk, WTk);
  transpose_w<<<dim3(32, 32), tb, 0, stream>>>(Wv, WTv);
  transpose_w<<<dim3(32, 32), tb, 0, stream>>>(Wo, WTo);

  // projections: convert input to bf16 (reusing buf0), then GEMM with permuted store
  cvt_bf16<<<8192, 256, 0, stream>>>((const float4*)q, (uint4*)buf0);
  gemm_tn<1, true><<<1024, 256, 0, stream>>>(buf0, WTq, qh, 1024, 1024, 1024, 1024, 8, 0, 0, 0);
  cvt_bf16<<<8192, 256, 0, stream>>>((const float4*)k, (uint4*)buf0);
  gemm_tn<1, true><<<1024, 256, 0, stream>>>(buf0, WTk, kh, 1024, 1024, 1024, 1024, 8, 0, 0, 0);
  cvt_bf16<<<8192, 256, 0, stream>>>((const float4*)v, (uint4*)buf0);
  gemm_tn<1, true><<<1024, 256, 0, stream>>>(buf0, WTv, vh, 1024, 1024, 1024, 1024, 8, 0, 0, 0);

  transpose_v<<<dim3(32, 8, BHN), tb, 0, stream>>>(vh, vhT);

  // scores: per bh, S[256][256] = qh @ kh^T (raw fp32) -> Sc aliases buf0
  gemm_tn<0, false><<<dim3(2, 2, BHN), 256, 0, stream>>>(qh, kh, Sc, 1024, 1024, 1024, 256, 2,
                                                         (long)256 * 1024, (long)256 * 1024,
                                                         (long)65536);
  // scale + mask + softmax -> att bf16 (aliases qh; qh dead after scores)
  softmax_mask<<<4096, 256, 0, stream>>>(Sc, mask, att);

  // PV: per bh, x[256][1024] = att @ vh ; permuted store to [b][s][d] (x aliases kh)
  gemm_tn<2, false><<<dim3(8, 2, BHN), 256, 0, stream>>>(att, vhT, x, 256, 256, 256, 1024, 8,
                                                         (long)65536, (long)262144, 0);

  // out = x @ Wo, fp32
  gemm_tn<0, true><<<1024, 256, 0, stream>>>(x, WTo, out, 1024, 1024, 1024, 1024, 8, 0, 0, 0);
}

// Round 3
// 292.083 us; speedup vs baseline: 2.4911x; 1.1069x over previous
//
#include <hip/hip_runtime.h>
#include <hip/hip_bf16.h>

typedef __bf16 bf16x8 __attribute__((ext_vector_type(8)));
typedef float f32x4 __attribute__((ext_vector_type(4)));
typedef unsigned short ushort_t;
typedef unsigned int uint_t;

#define HN 16
#define LSEQ 256
#define DD 1024
#define BB 4
#define SS 4096
#define MROWS (BB * SS) /* 16384 */
#define BHN (BB * HN)   /* 64 */

__device__ __forceinline__ ushort_t f2bf(float f) {
  uint_t u = __builtin_bit_cast(uint_t, f);
  u += 0x7fffu + ((u >> 16) & 1u); // RNE
  return (ushort_t)(u >> 16);
}
__device__ __forceinline__ uint_t pk2(float lo, float hi) {
  return (uint_t)f2bf(lo) | ((uint_t)f2bf(hi) << 16);
}

// ---------- fp32 -> bf16 bulk convert (8 elems/thread) ----------
__global__ __launch_bounds__(256) void cvt_bf16(const float4* __restrict__ in,
                                                uint4* __restrict__ out) {
  const long i = (long)blockIdx.x * 256 + threadIdx.x;
  const float4 a = in[i * 2];
  const float4 b = in[i * 2 + 1];
  uint4 o;
  o.x = pk2(a.x, a.y);
  o.y = pk2(a.z, a.w);
  o.z = pk2(b.x, b.y);
  o.w = pk2(b.z, b.w);
  out[i] = o;
}

// ---------- weight transpose: W fp32 [K][N] -> WT bf16 [N][K] ----------
__global__ __launch_bounds__(256) void transpose_w(const float* __restrict__ W,
                                                   ushort_t* __restrict__ WT) {
  __shared__ float tile[32][33];
  const int tx = threadIdx.x, ty = threadIdx.y;
  const int bn = blockIdx.x * 32, bk = blockIdx.y * 32;
#pragma unroll
  for (int j = 0; j < 32; j += 8)
    tile[ty + j][tx] = W[(long)(bk + ty + j) * DD + bn + tx];
  __syncthreads();
#pragma unroll
  for (int j = 0; j < 32; j += 8)
    WT[(long)(bn + ty + j) * DD + bk + tx] = f2bf(tile[tx][ty + j]);
}

// ---------- vh transpose per (b,h): [256][1024] -> [1024][256] bf16 ----------
__global__ __launch_bounds__(256) void transpose_v(const ushort_t* __restrict__ vh,
                                                   ushort_t* __restrict__ vhT) {
  __shared__ ushort_t tile[32][33];
  const int tx = threadIdx.x, ty = threadIdx.y;
  const long zo = (long)blockIdx.z * (LSEQ * DD);
  const ushort_t* src = vh + zo;
  ushort_t* dst = vhT + zo;
  const int bd = blockIdx.x * 32; // d
  const int bl = blockIdx.y * 32; // l
#pragma unroll
  for (int j = 0; j < 32; j += 8)
    tile[ty + j][tx] = src[(long)(bl + ty + j) * DD + bd + tx];
  __syncthreads();
#pragma unroll
  for (int j = 0; j < 32; j += 8)
    dst[(long)(bd + ty + j) * LSEQ + bl + tx] = tile[tx][ty + j];
}

// ---------- scale + mask + softmax: S fp32 [16384][256] -> att bf16 ----------
__global__ __launch_bounds__(256) void softmax_mask(const float* __restrict__ Sc,
                                                    const int* __restrict__ mask,
                                                    ushort_t* __restrict__ att) {
  const int wid = threadIdx.x >> 6, lane = threadIdx.x & 63;
  const int g = blockIdx.x * 4 + wid; // global row: bh*256 + l
  const int bh = g >> 8, l = g & 255;
  const int b = bh >> 4;
  const float4 sv = *(const float4*)&Sc[(long)g * 256 + lane * 4];
  const int4 mv = *(const int4*)&mask[((long)b * 256 + l) * 256 + lane * 4];
  float s[4];
  s[0] = (mv.x == 0) ? 1e-9f : sv.x * 0.03125f;
  s[1] = (mv.y == 0) ? 1e-9f : sv.y * 0.03125f;
  s[2] = (mv.z == 0) ? 1e-9f : sv.z * 0.03125f;
  s[3] = (mv.w == 0) ? 1e-9f : sv.w * 0.03125f;
  float mx = fmaxf(fmaxf(s[0], s[1]), fmaxf(s[2], s[3]));
#pragma unroll
  for (int off = 32; off; off >>= 1) mx = fmaxf(mx, __shfl_xor(mx, off));
  float e[4], sum = 0.f;
#pragma unroll
  for (int i = 0; i < 4; ++i) {
    e[i] = __expf(s[i] - mx);
    sum += e[i];
  }
#pragma unroll
  for (int off = 32; off; off >>= 1) sum += __shfl_xor(sum, off);
  const float inv = 1.0f / sum;
  ushort4 o;
  o.x = f2bf(e[0] * inv);
  o.y = f2bf(e[1] * inv);
  o.z = f2bf(e[2] * inv);
  o.w = f2bf(e[3] * inv);
  *(ushort4*)&att[(long)g * 256 + lane * 4] = o;
}

// ---------- OLD 128^2 TN GEMM (kept for batched scores / PV) ----------
// C[M][N] = A[M][K] * Bt[N][K]^T
// SMODE: 0 = fp32 plain store (ldC), 2 = bf16 pv-permute
template <int SMODE>
__global__ __launch_bounds__(256, 2) void gemm_tn(const ushort_t* __restrict__ Ab,
                                                  const ushort_t* __restrict__ Btp,
                                                  void* __restrict__ Cp, int K, int ldA,
                                                  int ldB, int ldC, long batchA,
                                                  long batchB, long batchC) {
  __shared__ ushort_t smem[16384];
  ushort_t* sA = smem;
  ushort_t* sB = smem + 8192;

  const int bx = blockIdx.x, by = blockIdx.y, z = blockIdx.z;
  const int rowBase = by * 128;
  const int colBase = bx * 128;

  const int t = threadIdx.x;
  const int lane = t & 63;
  const int wid = t >> 6;
  const int wr = (wid >> 1) * 64;
  const int wc = (wid & 1) * 64;
  const int fr = lane & 15;
  const int fk = (lane >> 4) * 8;

  const ushort_t* Atile = Ab + batchA * z + (long)rowBase * ldA;
  const ushort_t* Btile = Btp + batchB * z + (long)colBase * ldB;

  f32x4 acc[4][4];
#pragma unroll
  for (int m = 0; m < 4; ++m)
#pragma unroll
    for (int n = 0; n < 4; ++n) acc[m][n] = (f32x4){0.f, 0.f, 0.f, 0.f};

  const int NT = K >> 5;

  auto stageAB = [&](int buf, int kt) {
    const long ko = (long)kt * 32;
#pragma unroll
    for (int i = 0; i < 2; ++i) {
      const int c = i * 256 + t;
      const int cw = i * 256 + (t & 192);
      __builtin_amdgcn_global_load_lds(
          (const __attribute__((address_space(1))) void*)(Atile + (long)(c >> 2) * ldA + ko +
                                                          (c & 3) * 8),
          (__attribute__((address_space(3))) void*)(sA + buf * 4096 + cw * 8), 16, 0, 0);
      __builtin_amdgcn_global_load_lds(
          (const __attribute__((address_space(1))) void*)(Btile + (long)(c >> 2) * ldB + ko +
                                                          (c & 3) * 8),
          (__attribute__((address_space(3))) void*)(sB + buf * 4096 + cw * 8), 16, 0, 0);
    }
  };

  stageAB(0, 0);
  __syncthreads();

  int cur = 0;
  for (int kt = 0; kt < NT; ++kt) {
    if (kt + 1 < NT) stageAB(cur ^ 1, kt + 1);

    bf16x8 af[4], bfv[4];
    const ushort_t* baseA = sA + cur * 4096 + fk;
    const ushort_t* baseB = sB + cur * 4096 + fk;
#pragma unroll
    for (int m = 0; m < 4; ++m) af[m] = *(const bf16x8*)(baseA + (wr + m * 16 + fr) * 32);
#pragma unroll
    for (int n = 0; n < 4; ++n) bfv[n] = *(const bf16x8*)(baseB + (wc + n * 16 + fr) * 32);

#pragma unroll
    for (int m = 0; m < 4; ++m)
#pragma unroll
      for (int n = 0; n < 4; ++n)
        acc[m][n] = __builtin_amdgcn_mfma_f32_16x16x32_bf16(af[m], bfv[n], acc[m][n], 0, 0, 0);

    __syncthreads();
    cur ^= 1;
  }

  const int rq = (lane >> 4) * 4;
  if constexpr (SMODE == 0) {
    float* Cf = (float*)Cp + batchC * z;
#pragma unroll
    for (int m = 0; m < 4; ++m)
#pragma unroll
      for (int n = 0; n < 4; ++n)
#pragma unroll
        for (int r = 0; r < 4; ++r)
          Cf[(long)(rowBase + wr + m * 16 + rq + r) * ldC + colBase + wc + n * 16 + fr] =
              acc[m][n][r];
  } else {
#pragma unroll
    for (int m = 0; m < 4; ++m)
#pragma unroll
      for (int n = 0; n < 4; ++n)
#pragma unroll
        for (int r = 0; r < 4; ++r)
          smem[(wr + m * 16 + rq + r) * 128 + wc + n * 16 + fr] = f2bf(acc[m][n][r]);
    __syncthreads();
    ushort_t* Cb = (ushort_t*)Cp;
    const int c8 = (lane & 15) * 8;
#pragma unroll
    for (int i = 0; i < 8; ++i) {
      const int row = i * 16 + wid * 4 + (lane >> 4);
      const uint4 val = *(const uint4*)(smem + row * 128 + c8);
      const int l = rowBase + row;
      const int orow = ((z >> 4) << 12) + l * 16 + (z & 15); // b*4096 + l*16 + h
      *(uint4*)(Cb + (long)orow * 1024 + colBase + c8) = val;
    }
  }
}

// ---------- NEW 256^2 8-phase TN GEMM (non-batched), bf16 in ----------
// C[M][N] = A[M][K] * Bt[N][K]^T.  SMODE: 0 = fp32 direct, 1 = bf16 proj-permute.
// Requires: grid 1-D, nwg % 8 == 0; K % 128 == 0, K >= 256.
#define SBAR() asm volatile("s_barrier" ::: "memory")
#define LGKM0() asm volatile("s_waitcnt lgkmcnt(0)" ::: "memory")
#define VMW2() asm volatile("s_waitcnt vmcnt(2)" ::: "memory")
#define VMW0() asm volatile("s_waitcnt vmcnt(0)" ::: "memory")

template <int SMODE>
__global__ __launch_bounds__(512, 1) void gemm256(const ushort_t* __restrict__ Ab,
                                                  const ushort_t* __restrict__ Btp,
                                                  void* __restrict__ Cp, int K, int ldA,
                                                  int ldB, int ldC, int nbx) {
  __shared__ ushort_t sm[65536]; // 128 KiB: A dbuf 2x16384, B dbuf 2x16384; epilogue 256x256

  // bijective XCD-chunked swizzle (nwg % 8 == 0)
  const int orig = blockIdx.x;
  const int cpx = (int)gridDim.x >> 3;
  const int wgid = (orig & 7) * cpx + (orig >> 3);
  const int by = wgid / nbx, bx = wgid % nbx;
  const int rowBase = by * 256, colBase = bx * 256;

  const int t = threadIdx.x;
  const int lane = t & 63;
  const int wid = t >> 6;
  const int wm = wid >> 2;  // 0..1
  const int wn = wid & 3;   // 0..3
  const int fr = lane & 15;
  const int q = lane >> 4;

  // per-thread swizzled LDS read offsets (elems). row&7 == fr&7 for all frag rows.
  const int sw0 = ((q ^ (fr & 7)) * 8);
  const int sw1 = (((4 + q) ^ (fr & 7)) * 8);
  const int aoff0 = fr * 64 + sw0;
  const int aoff1 = fr * 64 + sw1;
  const int bbase = ((wn & 1) * 64 + fr) * 64;
  const int boff0 = bbase + sw0;
  const int boff1 = bbase + sw1;

  // staging: per half-tile (128 rows x 64 cols) each thread issues 2 x 16B loads.
  // chunk c = i*512 + t; row=c>>3, phys chunk=c&7 holds global chunk (c&7)^(row&7).
  const ushort_t* srcA[2][2];
  const ushort_t* srcB[2][2];
  int ldsoff[2];
#pragma unroll
  for (int i = 0; i < 2; ++i) {
    const int c = i * 512 + t;
    const int rowc = c >> 3;
    const int gc = (c & 7) ^ (rowc & 7);
    srcA[0][i] = Ab + (long)(rowBase + rowc) * ldA + gc * 8;
    srcA[1][i] = Ab + (long)(rowBase + 128 + rowc) * ldA + gc * 8;
    srcB[0][i] = Btp + (long)(colBase + rowc) * ldB + gc * 8;
    srcB[1][i] = Btp + (long)(colBase + 128 + rowc) * ldB + gc * 8;
    ldsoff[i] = (c & ~63) * 8; // wave-uniform base (elems)
  }

#define STAGE(kind, h, T)                                                                   \
  do {                                                                                      \
    ushort_t* _d = sm + ((kind) ? 32768 : 0) + ((T) & 1) * 16384 + (h) * 8192;              \
    const ushort_t* _s0 = ((kind) ? srcB[h][0] : srcA[h][0]) + (long)(T) * 64;              \
    __builtin_amdgcn_global_load_lds((const __attribute__((address_space(1))) void*)_s0,    \
                                     (__attribute__((address_space(3))) void*)(_d + ldsoff[0]), \
                                     16, 0, 0);                                             \
    const ushort_t* _s1 = ((kind) ? srcB[h][1] : srcA[h][1]) + (long)(T) * 64;              \
    __builtin_amdgcn_global_load_lds((const __attribute__((address_space(1))) void*)_s1,    \
                                     (__attribute__((address_space(3))) void*)(_d + ldsoff[1]), \
                                     16, 0, 0);                                             \
  } while (0)

  f32x4 acc[8][4];
#pragma unroll
  for (int m = 0; m < 8; ++m)
#pragma unroll
    for (int n = 0; n < 4; ++n) acc[m][n] = (f32x4){0.f, 0.f, 0.f, 0.f};

  bf16x8 af[4][2], bf0[2][2], bf1[2][2];

#define LDA4(dbuf, msub)                                                         \
  do {                                                                           \
    const ushort_t* _b = sm + (dbuf)*16384 + wm * 8192 + (msub)*4096;            \
    _Pragma("unroll") for (int m2 = 0; m2 < 4; ++m2) {                           \
      af[m2][0] = *(const bf16x8*)(_b + m2 * 1024 + aoff0);                      \
      af[m2][1] = *(const bf16x8*)(_b + m2 * 1024 + aoff1);                      \
    }                                                                            \
  } while (0)

#define LDB2(dbuf, nsub, bfv)                                                    \
  do {                                                                           \
    const ushort_t* _b = sm + 32768 + (dbuf)*16384 + (wn >> 1) * 8192 + (nsub)*2048; \
    _Pragma("unroll") for (int n2 = 0; n2 < 2; ++n2) {                           \
      bfv[n2][0] = *(const bf16x8*)(_b + n2 * 1024 + boff0);                     \
      bfv[n2][1] = *(const bf16x8*)(_b + n2 * 1024 + boff1);                     \
    }                                                                            \
  } while (0)

#define MMQ(msub, nsub, bfv)                                                     \
  do {                                                                           \
    _Pragma("unroll") for (int m2 = 0; m2 < 4; ++m2)                             \
        _Pragma("unroll") for (int n2 = 0; n2 < 2; ++n2) {                       \
      acc[(msub)*4 + m2][(nsub)*2 + n2] = __builtin_amdgcn_mfma_f32_16x16x32_bf16( \
          af[m2][0], bfv[n2][0], acc[(msub)*4 + m2][(nsub)*2 + n2], 0, 0, 0);    \
      acc[(msub)*4 + m2][(nsub)*2 + n2] = __builtin_amdgcn_mfma_f32_16x16x32_bf16( \
          af[m2][1], bfv[n2][1], acc[(msub)*4 + m2][(nsub)*2 + n2], 0, 0, 0);    \
    }                                                                            \
  } while (0)

#define PH_OPEN() SBAR(); LGKM0(); __builtin_amdgcn_s_setprio(1)
#define PH_CLOSE() __builtin_amdgcn_s_setprio(0); SBAR()

  const int NT = K >> 6;  // K-tiles of 64
  const int NI = NT >> 1; // iterations (2 K-tiles each)

  // prologue: K0 fully + A0(K1); wait K0 complete (own 8 oldest loads)
  STAGE(0, 0, 0);
  STAGE(0, 1, 0);
  STAGE(1, 0, 0);
  STAGE(1, 1, 0);
  STAGE(0, 0, 1);
  VMW2();
  SBAR();

  for (int it = 0; it < NI - 1; ++it) {
    const int T0 = 2 * it;
    // Ph1
    LDA4(0, 0);
    LDB2(0, 0, bf0);
    STAGE(0, 1, T0 + 1);
    PH_OPEN(); MMQ(0, 0, bf0); PH_CLOSE();
    // Ph2
    LDB2(0, 1, bf1);
    STAGE(1, 0, T0 + 1);
    PH_OPEN(); MMQ(0, 1, bf1); PH_CLOSE();
    // Ph3
    LDA4(0, 1);
    STAGE(1, 1, T0 + 1);
    PH_OPEN(); MMQ(1, 1, bf1); PH_CLOSE();
    // Ph4 (no reads; stage into dbuf0 — safe: all dbuf0 reads drained by Ph3 close)
    STAGE(0, 0, T0 + 2);
    SBAR();
    __builtin_amdgcn_s_setprio(1);
    MMQ(1, 0, bf0);
    __builtin_amdgcn_s_setprio(0);
    VMW2(); // K(T0+1) fully staged (oldest 8 of 10)
    SBAR();
    // Ph5
    LDA4(1, 0);
    LDB2(1, 0, bf0);
    STAGE(0, 1, T0 + 2);
    PH_OPEN(); MMQ(0, 0, bf0); PH_CLOSE();
    // Ph6
    LDB2(1, 1, bf1);
    STAGE(1, 0, T0 + 2);
    PH_OPEN(); MMQ(0, 1, bf1); PH_CLOSE();
    // Ph7
    LDA4(1, 1);
    STAGE(1, 1, T0 + 2);
    PH_OPEN(); MMQ(1, 1, bf1); PH_CLOSE();
    // Ph8
    STAGE(0, 0, T0 + 3);
    SBAR();
    __builtin_amdgcn_s_setprio(1);
    MMQ(1, 0, bf0);
    __builtin_amdgcn_s_setprio(0);
    VMW2(); // K(T0+2) fully staged
    SBAR();
  }

  // peeled last iteration (K-tiles NT-2, NT-1): finish staging K(NT-1), no new stages
  {
    // Ph1
    LDA4(0, 0);
    LDB2(0, 0, bf0);
    STAGE(0, 1, NT - 1);
    PH_OPEN(); MMQ(0, 0, bf0); PH_CLOSE();
    // Ph2
    LDB2(0, 1, bf1);
    STAGE(1, 0, NT - 1);
    PH_OPEN(); MMQ(0, 1, bf1); PH_CLOSE();
    // Ph3
    LDA4(0, 1);
    STAGE(1, 1, NT - 1);
    PH_OPEN(); MMQ(1, 1, bf1); PH_CLOSE();
    // Ph4
    SBAR();
    __builtin_amdgcn_s_setprio(1);
    MMQ(1, 0, bf0);
    __builtin_amdgcn_s_setprio(0);
    VMW0();
    SBAR();
    // Ph5
    LDA4(1, 0);
    LDB2(1, 0, bf0);
    PH_OPEN(); MMQ(0, 0, bf0); PH_CLOSE();
    // Ph6
    LDB2(1, 1, bf1);
    PH_OPEN(); MMQ(0, 1, bf1); PH_CLOSE();
    // Ph7
    LDA4(1, 1);
    PH_OPEN(); MMQ(1, 1, bf1); PH_CLOSE();
    // Ph8
    SBAR();
    MMQ(1, 0, bf0);
    SBAR();
  }

  // ---------------- epilogue ----------------
  const int rq = q * 4;
  if constexpr (SMODE == 0) {
    float* Cf = (float*)Cp;
#pragma unroll
    for (int m = 0; m < 8; ++m)
#pragma unroll
      for (int n = 0; n < 4; ++n)
#pragma unroll
        for (int r = 0; r < 4; ++r) {
          const int row = rowBase + wm * 128 + m * 16 + rq + r;
          const int col = colBase + wn * 64 + n * 16 + fr;
          Cf[(long)row * ldC + col] = acc[m][n][r];
        }
  } else {
    // stage 256x256 bf16 C-tile in LDS (16B-chunk XOR swizzle), then permuted row stores
#pragma unroll
    for (int m = 0; m < 8; ++m)
#pragma unroll
      for (int n = 0; n < 4; ++n)
#pragma unroll
        for (int r = 0; r < 4; ++r) {
          const int row = wm * 128 + m * 16 + rq + r;
          const int col = wn * 64 + n * 16 + fr;
          sm[row * 256 + (((col >> 3) ^ (row & 7)) * 8) + (col & 7)] = f2bf(acc[m][n][r]);
        }
    __syncthreads();
    ushort_t* Cb = (ushort_t*)Cp;
    const int cc = t & 31;
    const int r0 = t >> 5;
#pragma unroll
    for (int i = 0; i < 16; ++i) {
      const int row = r0 + i * 16;
      const uint4 val = *(const uint4*)(sm + row * 256 + ((cc ^ (row & 7)) * 8));
      const int grow = rowBase + row; // = b*4096 + s, s = l*16+h
      const int b = grow >> 12;
      const int s = grow & 4095;
      const int orow = ((b << 4) + (s & 15)) * 256 + (s >> 4); // (b*16+h)*256 + l
      *(uint4*)(Cb + (long)orow * 1024 + colBase + cc * 8) = val;
    }
  }
#undef STAGE
#undef LDA4
#undef LDB2
#undef MMQ
#undef PH_OPEN
#undef PH_CLOSE
}

extern "C" void kernel_launch(void* const* d_in, const int* in_sizes, int n_in,
                              void* d_out, int out_size, void* d_ws, size_t ws_size,
                              hipStream_t stream) {
  const float* q = (const float*)d_in[0];
  const float* k = (const float*)d_in[1];
  const float* v = (const float*)d_in[2];
  const int* mask = (const int*)d_in[3];
  const float* Wq = (const float*)d_in[4];
  const float* Wk = (const float*)d_in[5];
  const float* Wv = (const float*)d_in[6];
  const float* Wo = (const float*)d_in[7];
  float* out = (float*)d_out;

  // workspace layout (peak 168 MiB), with aliasing:
  char* ws = (char*)d_ws;
  const size_t MB = 1024 * 1024;
  ushort_t* WTq = (ushort_t*)(ws + 0 * MB);
  ushort_t* WTk = (ushort_t*)(ws + 2 * MB);
  ushort_t* WTv = (ushort_t*)(ws + 4 * MB);
  ushort_t* WTo = (ushort_t*)(ws + 6 * MB);
  ushort_t* buf0 = (ushort_t*)(ws + 8 * MB);  // qb/kb/vb (32MB), later Sc (16MB? fp32 64MB fits)
  ushort_t* qh = (ushort_t*)(ws + 40 * MB);   // later att (8MB)
  ushort_t* kh = (ushort_t*)(ws + 72 * MB);   // later x (32MB)
  ushort_t* vh = (ushort_t*)(ws + 104 * MB);
  ushort_t* vhT = (ushort_t*)(ws + 136 * MB);
  float* Sc = (float*)buf0;
  ushort_t* att = qh;
  ushort_t* x = kh;

  const dim3 tb(32, 8);
  transpose_w<<<dim3(32, 32), tb, 0, stream>>>(Wq, WTq);
  transpose_w<<<dim3(32, 32), tb, 0, stream>>>(Wk, WTk);
  transpose_w<<<dim3(32, 32), tb, 0, stream>>>(Wv, WTv);
  transpose_w<<<dim3(32, 32), tb, 0, stream>>>(Wo, WTo);

  // projections: convert input to bf16 (reusing buf0), then 256^2 8-phase GEMM
  cvt_bf16<<<8192, 256, 0, stream>>>((const float4*)q, (uint4*)buf0);
  gemm256<1><<<256, 512, 0, stream>>>(buf0, WTq, qh, 1024, 1024, 1024, 1024, 4);
  cvt_bf16<<<8192, 256, 0, stream>>>((const float4*)k, (uint4*)buf0);
  gemm256<1><<<256, 512, 0, stream>>>(buf0, WTk, kh, 1024, 1024, 1024, 1024, 4);
  cvt_bf16<<<8192, 256, 0, stream>>>((const float4*)v, (uint4*)buf0);
  gemm256<1><<<256, 512, 0, stream>>>(buf0, WTv, vh, 1024, 1024, 1024, 1024, 4);

  transpose_v<<<dim3(32, 8, BHN), tb, 0, stream>>>(vh, vhT);

  // scores: per bh, S[256][256] = qh @ kh^T (raw fp32) -> Sc aliases buf0
  gemm_tn<0><<<dim3(2, 2, BHN), 256, 0, stream>>>(qh, kh, Sc, 1024, 1024, 1024, 256,
                                                  (long)256 * 1024, (long)256 * 1024,
                                                  (long)65536);
  // scale + mask + softmax -> att bf16 (aliases qh; qh dead after scores)
  softmax_mask<<<4096, 256, 0, stream>>>(Sc, mask, att);

  // PV: per bh, x[256][1024] = att @ vh ; permuted store to [b][s][d] (x aliases kh)
  gemm_tn<2><<<dim3(8, 2, BHN), 256, 0, stream>>>(att, vhT, x, 256, 256, 256, 1024,
                                                  (long)65536, (long)262144, 0);

  // out = x @ Wo, fp32
  gemm256<0><<<256, 512, 0, stream>>>(x, WTo, out, 1024, 1024, 1024, 1024, 4);
}

// Round 4
// 270.515 us; speedup vs baseline: 2.6897x; 1.0797x over previous
//
#include <hip/hip_runtime.h>
#include <hip/hip_bf16.h>

typedef __bf16 bf16x8 __attribute__((ext_vector_type(8)));
typedef float f32x4 __attribute__((ext_vector_type(4)));
typedef unsigned short ushort_t;
typedef unsigned int uint_t;

#define HN 16
#define LSEQ 256
#define DD 1024
#define BB 4
#define SS 4096
#define MROWS (BB * SS) /* 16384 */
#define BHN (BB * HN)   /* 64 */

__device__ __forceinline__ ushort_t f2bf(float f) {
  uint_t u = __builtin_bit_cast(uint_t, f);
  u += 0x7fffu + ((u >> 16) & 1u); // RNE
  return (ushort_t)(u >> 16);
}
__device__ __forceinline__ uint_t pk2(float lo, float hi) {
  return (uint_t)f2bf(lo) | ((uint_t)f2bf(hi) << 16);
}

// ---------- fp32 -> bf16 bulk convert, up to 3 sources (z picks) ----------
__global__ __launch_bounds__(256) void cvt3(const float4* __restrict__ s0,
                                            const float4* __restrict__ s1,
                                            const float4* __restrict__ s2,
                                            uint4* __restrict__ out) {
  const int z = blockIdx.y;
  const float4* in = (z == 0) ? s0 : (z == 1) ? s1 : s2;
  const long i = (long)blockIdx.x * 256 + threadIdx.x;
  const float4 a = in[i * 2];
  const float4 b = in[i * 2 + 1];
  uint4 o;
  o.x = pk2(a.x, a.y);
  o.y = pk2(a.z, a.w);
  o.z = pk2(b.x, b.y);
  o.w = pk2(b.z, b.w);
  out[(long)z * 2097152 + i] = o;
}

// ---------- weight transpose x4: W fp32 [K][N] -> WT bf16 [N][K], packed ----------
__global__ __launch_bounds__(256) void transpose_w4(const float* __restrict__ W0,
                                                    const float* __restrict__ W1,
                                                    const float* __restrict__ W2,
                                                    const float* __restrict__ W3,
                                                    ushort_t* __restrict__ WT) {
  __shared__ float tile[32][33];
  const int z = blockIdx.z;
  const float* W = (z == 0) ? W0 : (z == 1) ? W1 : (z == 2) ? W2 : W3;
  ushort_t* dst = WT + (long)z * 1048576;
  const int tx = threadIdx.x, ty = threadIdx.y;
  const int bn = blockIdx.x * 32, bk = blockIdx.y * 32;
#pragma unroll
  for (int j = 0; j < 32; j += 8)
    tile[ty + j][tx] = W[(long)(bk + ty + j) * DD + bn + tx];
  __syncthreads();
#pragma unroll
  for (int j = 0; j < 32; j += 8)
    dst[(long)(bn + ty + j) * DD + bk + tx] = f2bf(tile[tx][ty + j]);
}

// ---------- vh transpose per (b,h): [256][1024] -> [1024][256] bf16 ----------
__global__ __launch_bounds__(256) void transpose_v(const ushort_t* __restrict__ vh,
                                                   ushort_t* __restrict__ vhT) {
  __shared__ ushort_t tile[32][33];
  const int tx = threadIdx.x, ty = threadIdx.y;
  const long zo = (long)blockIdx.z * (LSEQ * DD);
  const ushort_t* src = vh + zo;
  ushort_t* dst = vhT + zo;
  const int bd = blockIdx.x * 32; // d
  const int bl = blockIdx.y * 32; // l
#pragma unroll
  for (int j = 0; j < 32; j += 8)
    tile[ty + j][tx] = src[(long)(bl + ty + j) * DD + bd + tx];
  __syncthreads();
#pragma unroll
  for (int j = 0; j < 32; j += 8)
    dst[(long)(bd + ty + j) * LSEQ + bl + tx] = tile[tx][ty + j];
}

// ---------- fused scores + mask + softmax ----------
// per block: one (b,h), 64 q-rows, all 256 k-cols, K=1024. att bf16 out.
__global__ __launch_bounds__(256, 2) void score_sm(const ushort_t* __restrict__ qh,
                                                   const ushort_t* __restrict__ kh,
                                                   const int* __restrict__ mask,
                                                   ushort_t* __restrict__ att) {
  __shared__ char smemraw[81920]; // staging A 16KB + B 64KB; epilogue S 64KB aliases
  ushort_t* sA = (ushort_t*)smemraw;           // 2 x 4096 elems
  ushort_t* sB = (ushort_t*)(smemraw + 16384); // 2 x 16384 elems
  float* Sf = (float*)smemraw;                 // [64][256] fp32

  const int orig = blockIdx.x;
  const int wgid = (orig & 7) * 32 + (orig >> 3); // XCD-chunked, 256 % 8 == 0
  const int bh = wgid >> 2, rb = wgid & 3;
  const int b = bh >> 4;
  const ushort_t* A = qh + ((long)bh * 256 + rb * 64) * 1024;
  const ushort_t* Bk = kh + (long)bh * 256 * 1024;

  const int t = threadIdx.x, lane = t & 63, wid = t >> 6;
  const int fr = lane & 15, q = lane >> 4;
  const int wc = wid * 64;
  const int sw0 = (q ^ (fr & 7)) * 8;
  const int sw1 = ((4 + q) ^ (fr & 7)) * 8;

  // staging offsets (XOR-chunk swizzle: phys chunk c&7 holds global chunk (c&7)^(row&7))
  int srcAo[2], dstA[2], srcBo[8], dstB[8];
#pragma unroll
  for (int i = 0; i < 2; ++i) {
    const int c = i * 256 + t, row = c >> 3, gc = (c & 7) ^ (row & 7);
    srcAo[i] = row * 1024 + gc * 8;
    dstA[i] = (i * 256 + (t & 192)) * 8;
  }
#pragma unroll
  for (int i = 0; i < 8; ++i) {
    const int c = i * 256 + t, row = c >> 3, gc = (c & 7) ^ (row & 7);
    srcBo[i] = row * 1024 + gc * 8;
    dstB[i] = (i * 256 + (t & 192)) * 8;
  }

  auto stage = [&](int buf, int kt) {
    const int ko = kt * 64;
#pragma unroll
    for (int i = 0; i < 2; ++i)
      __builtin_amdgcn_global_load_lds(
          (const __attribute__((address_space(1))) void*)(A + srcAo[i] + ko),
          (__attribute__((address_space(3))) void*)(sA + buf * 4096 + dstA[i]), 16, 0, 0);
#pragma unroll
    for (int i = 0; i < 8; ++i)
      __builtin_amdgcn_global_load_lds(
          (const __attribute__((address_space(1))) void*)(Bk + srcBo[i] + ko),
          (__attribute__((address_space(3))) void*)(sB + buf * 16384 + dstB[i]), 16, 0, 0);
  };

  f32x4 acc[4][4];
#pragma unroll
  for (int m = 0; m < 4; ++m)
#pragma unroll
    for (int n = 0; n < 4; ++n) acc[m][n] = (f32x4){0.f, 0.f, 0.f, 0.f};

  stage(0, 0);
  __syncthreads();
  int cur = 0;
  for (int kt = 0; kt < 16; ++kt) {
    if (kt < 15) stage(cur ^ 1, kt + 1);
    bf16x8 af[4][2], bfv[4][2];
    const ushort_t* bA = sA + cur * 4096;
    const ushort_t* bB = sB + cur * 16384;
#pragma unroll
    for (int m = 0; m < 4; ++m) {
      af[m][0] = *(const bf16x8*)(bA + (m * 16 + fr) * 64 + sw0);
      af[m][1] = *(const bf16x8*)(bA + (m * 16 + fr) * 64 + sw1);
    }
#pragma unroll
    for (int n = 0; n < 4; ++n) {
      bfv[n][0] = *(const bf16x8*)(bB + (wc + n * 16 + fr) * 64 + sw0);
      bfv[n][1] = *(const bf16x8*)(bB + (wc + n * 16 + fr) * 64 + sw1);
    }
#pragma unroll
    for (int m = 0; m < 4; ++m)
#pragma unroll
      for (int n = 0; n < 4; ++n) {
        acc[m][n] = __builtin_amdgcn_mfma_f32_16x16x32_bf16(af[m][0], bfv[n][0], acc[m][n], 0, 0, 0);
        acc[m][n] = __builtin_amdgcn_mfma_f32_16x16x32_bf16(af[m][1], bfv[n][1], acc[m][n], 0, 0, 0);
      }
    __syncthreads();
    cur ^= 1;
  }

  // raw S tile -> LDS
#pragma unroll
  for (int m = 0; m < 4; ++m)
#pragma unroll
    for (int n = 0; n < 4; ++n)
#pragma unroll
      for (int r = 0; r < 4; ++r)
        Sf[(m * 16 + q * 4 + r) * 256 + wc + n * 16 + fr] = acc[m][n][r];
  __syncthreads();

  // wave-per-row softmax (16 rows/wave)
#pragma unroll 2
  for (int i = 0; i < 16; ++i) {
    const int row = wid * 16 + i;
    const int gl = rb * 64 + row;
    const f32x4 sv = *(const f32x4*)&Sf[row * 256 + lane * 4];
    const int4 mv = *(const int4*)&mask[((long)b * 256 + gl) * 256 + lane * 4];
    float s[4];
    s[0] = (mv.x == 0) ? 1e-9f : sv[0] * 0.03125f;
    s[1] = (mv.y == 0) ? 1e-9f : sv[1] * 0.03125f;
    s[2] = (mv.z == 0) ? 1e-9f : sv[2] * 0.03125f;
    s[3] = (mv.w == 0) ? 1e-9f : sv[3] * 0.03125f;
    float mx = fmaxf(fmaxf(s[0], s[1]), fmaxf(s[2], s[3]));
#pragma unroll
    for (int off = 32; off; off >>= 1) mx = fmaxf(mx, __shfl_xor(mx, off));
    float e[4], sum = 0.f;
#pragma unroll
    for (int j = 0; j < 4; ++j) {
      e[j] = __expf(s[j] - mx);
      sum += e[j];
    }
#pragma unroll
    for (int off = 32; off; off >>= 1) sum += __shfl_xor(sum, off);
    const float inv = 1.0f / sum;
    ushort4 o;
    o.x = f2bf(e[0] * inv);
    o.y = f2bf(e[1] * inv);
    o.z = f2bf(e[2] * inv);
    o.w = f2bf(e[3] * inv);
    *(ushort4*)&att[((long)bh * 256 + gl) * 256 + lane * 4] = o;
  }
}

// ---------- 128^2 TN GEMM (kept for batched PV) ----------
// SMODE: 2 = bf16 pv-permute store
template <int SMODE>
__global__ __launch_bounds__(256, 2) void gemm_tn(const ushort_t* __restrict__ Ab,
                                                  const ushort_t* __restrict__ Btp,
                                                  void* __restrict__ Cp, int K, int ldA,
                                                  int ldB, int ldC, long batchA,
                                                  long batchB, long batchC) {
  __shared__ ushort_t smem[16384];
  ushort_t* sA = smem;
  ushort_t* sB = smem + 8192;

  const int bx = blockIdx.x, by = blockIdx.y, z = blockIdx.z;
  const int rowBase = by * 128;
  const int colBase = bx * 128;

  const int t = threadIdx.x;
  const int lane = t & 63;
  const int wid = t >> 6;
  const int wr = (wid >> 1) * 64;
  const int wc = (wid & 1) * 64;
  const int fr = lane & 15;
  const int fk = (lane >> 4) * 8;

  const ushort_t* Atile = Ab + batchA * z + (long)rowBase * ldA;
  const ushort_t* Btile = Btp + batchB * z + (long)colBase * ldB;

  f32x4 acc[4][4];
#pragma unroll
  for (int m = 0; m < 4; ++m)
#pragma unroll
    for (int n = 0; n < 4; ++n) acc[m][n] = (f32x4){0.f, 0.f, 0.f, 0.f};

  const int NT = K >> 5;

  auto stageAB = [&](int buf, int kt) {
    const long ko = (long)kt * 32;
#pragma unroll
    for (int i = 0; i < 2; ++i) {
      const int c = i * 256 + t;
      const int cw = i * 256 + (t & 192);
      __builtin_amdgcn_global_load_lds(
          (const __attribute__((address_space(1))) void*)(Atile + (long)(c >> 2) * ldA + ko +
                                                          (c & 3) * 8),
          (__attribute__((address_space(3))) void*)(sA + buf * 4096 + cw * 8), 16, 0, 0);
      __builtin_amdgcn_global_load_lds(
          (const __attribute__((address_space(1))) void*)(Btile + (long)(c >> 2) * ldB + ko +
                                                          (c & 3) * 8),
          (__attribute__((address_space(3))) void*)(sB + buf * 4096 + cw * 8), 16, 0, 0);
    }
  };

  stageAB(0, 0);
  __syncthreads();

  int cur = 0;
  for (int kt = 0; kt < NT; ++kt) {
    if (kt + 1 < NT) stageAB(cur ^ 1, kt + 1);

    bf16x8 af[4], bfv[4];
    const ushort_t* baseA = sA + cur * 4096 + fk;
    const ushort_t* baseB = sB + cur * 4096 + fk;
#pragma unroll
    for (int m = 0; m < 4; ++m) af[m] = *(const bf16x8*)(baseA + (wr + m * 16 + fr) * 32);
#pragma unroll
    for (int n = 0; n < 4; ++n) bfv[n] = *(const bf16x8*)(baseB + (wc + n * 16 + fr) * 32);

#pragma unroll
    for (int m = 0; m < 4; ++m)
#pragma unroll
      for (int n = 0; n < 4; ++n)
        acc[m][n] = __builtin_amdgcn_mfma_f32_16x16x32_bf16(af[m], bfv[n], acc[m][n], 0, 0, 0);

    __syncthreads();
    cur ^= 1;
  }

  const int rq = (lane >> 4) * 4;
  {
#pragma unroll
    for (int m = 0; m < 4; ++m)
#pragma unroll
      for (int n = 0; n < 4; ++n)
#pragma unroll
        for (int r = 0; r < 4; ++r)
          smem[(wr + m * 16 + rq + r) * 128 + wc + n * 16 + fr] = f2bf(acc[m][n][r]);
    __syncthreads();
    ushort_t* Cb = (ushort_t*)Cp;
    const int c8 = (lane & 15) * 8;
#pragma unroll
    for (int i = 0; i < 8; ++i) {
      const int row = i * 16 + wid * 4 + (lane >> 4);
      const uint4 val = *(const uint4*)(smem + row * 128 + c8);
      const int l = rowBase + row;
      const int orow = ((z >> 4) << 12) + l * 16 + (z & 15); // b*4096 + l*16 + h
      *(uint4*)(Cb + (long)orow * 1024 + colBase + c8) = val;
    }
  }
}

// ---------- 256^2 8-phase TN GEMM, z-batched (up to 3 A matrices) ----------
// C_z[M][1024] = A_z[M][1024] * Bt_z[1024][1024]^T ; K = 1024 fixed.
// SMODE: 0 = fp32 direct, 1 = bf16 proj-permute. grid: nz*256 blocks, 512 thr.
#define SBAR() asm volatile("s_barrier" ::: "memory")
#define LGKM0() asm volatile("s_waitcnt lgkmcnt(0)" ::: "memory")
#define VMW2() asm volatile("s_waitcnt vmcnt(2)" ::: "memory")
#define VMW0() asm volatile("s_waitcnt vmcnt(0)" ::: "memory")

template <int SMODE>
__global__ __launch_bounds__(512, 1) void gemm256(const ushort_t* __restrict__ A0,
                                                  const ushort_t* __restrict__ A1,
                                                  const ushort_t* __restrict__ A2,
                                                  const ushort_t* __restrict__ Btp,
                                                  void* __restrict__ Cp, long bStrideZ,
                                                  long cStrideZ) {
  __shared__ ushort_t sm[65536]; // 128 KiB

  const int orig = blockIdx.x;
  const int cpx = (int)gridDim.x >> 3;
  const int wgid = (orig & 7) * cpx + (orig >> 3); // bijective (grid % 8 == 0)
  const int z = wgid >> 8;
  const int tile = wgid & 255;
  const int by = tile >> 2, bx = tile & 3;
  const int rowBase = by * 256, colBase = bx * 256;

  const ushort_t* Ab = (z == 0) ? A0 : (z == 1) ? A1 : A2;
  const ushort_t* Bt = Btp + bStrideZ * z;

  const int t = threadIdx.x;
  const int lane = t & 63;
  const int wid = t >> 6;
  const int wm = wid >> 2; // 0..1
  const int wn = wid & 3;  // 0..3
  const int fr = lane & 15;
  const int q = lane >> 4;

  const int sw0 = ((q ^ (fr & 7)) * 8);
  const int sw1 = (((4 + q) ^ (fr & 7)) * 8);
  const int aoff0 = fr * 64 + sw0;
  const int aoff1 = fr * 64 + sw1;
  const int bbase = ((wn & 1) * 64 + fr) * 64;
  const int boff0 = bbase + sw0;
  const int boff1 = bbase + sw1;

  const ushort_t* srcA[2][2];
  const ushort_t* srcB[2][2];
  int ldsoff[2];
#pragma unroll
  for (int i = 0; i < 2; ++i) {
    const int c = i * 512 + t;
    const int rowc = c >> 3;
    const int gc = (c & 7) ^ (rowc & 7);
    srcA[0][i] = Ab + (long)(rowBase + rowc) * 1024 + gc * 8;
    srcA[1][i] = Ab + (long)(rowBase + 128 + rowc) * 1024 + gc * 8;
    srcB[0][i] = Bt + (long)(colBase + rowc) * 1024 + gc * 8;
    srcB[1][i] = Bt + (long)(colBase + 128 + rowc) * 1024 + gc * 8;
    ldsoff[i] = (c & ~63) * 8;
  }

#define STAGE(kind, h, T)                                                                   \
  do {                                                                                      \
    ushort_t* _d = sm + ((kind) ? 32768 : 0) + ((T) & 1) * 16384 + (h) * 8192;              \
    const ushort_t* _s0 = ((kind) ? srcB[h][0] : srcA[h][0]) + (long)(T) * 64;              \
    __builtin_amdgcn_global_load_lds((const __attribute__((address_space(1))) void*)_s0,    \
                                     (__attribute__((address_space(3))) void*)(_d + ldsoff[0]), \
                                     16, 0, 0);                                             \
    const ushort_t* _s1 = ((kind) ? srcB[h][1] : srcA[h][1]) + (long)(T) * 64;              \
    __builtin_amdgcn_global_load_lds((const __attribute__((address_space(1))) void*)_s1,    \
                                     (__attribute__((address_space(3))) void*)(_d + ldsoff[1]), \
                                     16, 0, 0);                                             \
  } while (0)

  f32x4 acc[8][4];
#pragma unroll
  for (int m = 0; m < 8; ++m)
#pragma unroll
    for (int n = 0; n < 4; ++n) acc[m][n] = (f32x4){0.f, 0.f, 0.f, 0.f};

  bf16x8 af[4][2], bf0[2][2], bf1[2][2];

#define LDA4(dbuf, msub)                                                         \
  do {                                                                           \
    const ushort_t* _b = sm + (dbuf)*16384 + wm * 8192 + (msub)*4096;            \
    _Pragma("unroll") for (int m2 = 0; m2 < 4; ++m2) {                           \
      af[m2][0] = *(const bf16x8*)(_b + m2 * 1024 + aoff0);                      \
      af[m2][1] = *(const bf16x8*)(_b + m2 * 1024 + aoff1);                      \
    }                                                                            \
  } while (0)

#define LDB2(dbuf, nsub, bfv)                                                    \
  do {                                                                           \
    const ushort_t* _b = sm + 32768 + (dbuf)*16384 + (wn >> 1) * 8192 + (nsub)*2048; \
    _Pragma("unroll") for (int n2 = 0; n2 < 2; ++n2) {                           \
      bfv[n2][0] = *(const bf16x8*)(_b + n2 * 1024 + boff0);                     \
      bfv[n2][1] = *(const bf16x8*)(_b + n2 * 1024 + boff1);                     \
    }                                                                            \
  } while (0)

#define MMQ(msub, nsub, bfv)                                                     \
  do {                                                                           \
    _Pragma("unroll") for (int m2 = 0; m2 < 4; ++m2)                             \
        _Pragma("unroll") for (int n2 = 0; n2 < 2; ++n2) {                       \
      acc[(msub)*4 + m2][(nsub)*2 + n2] = __builtin_amdgcn_mfma_f32_16x16x32_bf16( \
          af[m2][0], bfv[n2][0], acc[(msub)*4 + m2][(nsub)*2 + n2], 0, 0, 0);    \
      acc[(msub)*4 + m2][(nsub)*2 + n2] = __builtin_amdgcn_mfma_f32_16x16x32_bf16( \
          af[m2][1], bfv[n2][1], acc[(msub)*4 + m2][(nsub)*2 + n2], 0, 0, 0);    \
    }                                                                            \
  } while (0)

#define PH_OPEN() SBAR(); LGKM0(); __builtin_amdgcn_s_setprio(1)
#define PH_CLOSE() __builtin_amdgcn_s_setprio(0); SBAR()

  const int NT = 16; // K=1024, K-tiles of 64
  const int NI = 8;

  STAGE(0, 0, 0);
  STAGE(0, 1, 0);
  STAGE(1, 0, 0);
  STAGE(1, 1, 0);
  STAGE(0, 0, 1);
  VMW2();
  SBAR();

  for (int it = 0; it < NI - 1; ++it) {
    const int T0 = 2 * it;
    LDA4(0, 0);
    LDB2(0, 0, bf0);
    STAGE(0, 1, T0 + 1);
    PH_OPEN(); MMQ(0, 0, bf0); PH_CLOSE();
    LDB2(0, 1, bf1);
    STAGE(1, 0, T0 + 1);
    PH_OPEN(); MMQ(0, 1, bf1); PH_CLOSE();
    LDA4(0, 1);
    STAGE(1, 1, T0 + 1);
    PH_OPEN(); MMQ(1, 1, bf1); PH_CLOSE();
    STAGE(0, 0, T0 + 2);
    SBAR();
    __builtin_amdgcn_s_setprio(1);
    MMQ(1, 0, bf0);
    __builtin_amdgcn_s_setprio(0);
    VMW2();
    SBAR();
    LDA4(1, 0);
    LDB2(1, 0, bf0);
    STAGE(0, 1, T0 + 2);
    PH_OPEN(); MMQ(0, 0, bf0); PH_CLOSE();
    LDB2(1, 1, bf1);
    STAGE(1, 0, T0 + 2);
    PH_OPEN(); MMQ(0, 1, bf1); PH_CLOSE();
    LDA4(1, 1);
    STAGE(1, 1, T0 + 2);
    PH_OPEN(); MMQ(1, 1, bf1); PH_CLOSE();
    STAGE(0, 0, T0 + 3);
    SBAR();
    __builtin_amdgcn_s_setprio(1);
    MMQ(1, 0, bf0);
    __builtin_amdgcn_s_setprio(0);
    VMW2();
    SBAR();
  }

  { // peeled last iteration (K-tiles NT-2, NT-1)
    LDA4(0, 0);
    LDB2(0, 0, bf0);
    STAGE(0, 1, NT - 1);
    PH_OPEN(); MMQ(0, 0, bf0); PH_CLOSE();
    LDB2(0, 1, bf1);
    STAGE(1, 0, NT - 1);
    PH_OPEN(); MMQ(0, 1, bf1); PH_CLOSE();
    LDA4(0, 1);
    STAGE(1, 1, NT - 1);
    PH_OPEN(); MMQ(1, 1, bf1); PH_CLOSE();
    SBAR();
    __builtin_amdgcn_s_setprio(1);
    MMQ(1, 0, bf0);
    __builtin_amdgcn_s_setprio(0);
    VMW0();
    SBAR();
    LDA4(1, 0);
    LDB2(1, 0, bf0);
    PH_OPEN(); MMQ(0, 0, bf0); PH_CLOSE();
    LDB2(1, 1, bf1);
    PH_OPEN(); MMQ(0, 1, bf1); PH_CLOSE();
    LDA4(1, 1);
    PH_OPEN(); MMQ(1, 1, bf1); PH_CLOSE();
    SBAR();
    MMQ(1, 0, bf0);
    SBAR();
  }

  const int rq = q * 4;
  if constexpr (SMODE == 0) {
    float* Cf = (float*)Cp + cStrideZ * z;
#pragma unroll
    for (int m = 0; m < 8; ++m)
#pragma unroll
      for (int n = 0; n < 4; ++n)
#pragma unroll
        for (int r = 0; r < 4; ++r) {
          const int row = rowBase + wm * 128 + m * 16 + rq + r;
          const int col = colBase + wn * 64 + n * 16 + fr;
          Cf[(long)row * 1024 + col] = acc[m][n][r];
        }
  } else {
#pragma unroll
    for (int m = 0; m < 8; ++m)
#pragma unroll
      for (int n = 0; n < 4; ++n)
#pragma unroll
        for (int r = 0; r < 4; ++r) {
          const int row = wm * 128 + m * 16 + rq + r;
          const int col = wn * 64 + n * 16 + fr;
          sm[row * 256 + (((col >> 3) ^ (row & 7)) * 8) + (col & 7)] = f2bf(acc[m][n][r]);
        }
    __syncthreads();
    ushort_t* Cb = (ushort_t*)Cp + cStrideZ * z;
    const int cc = t & 31;
    const int r0 = t >> 5;
#pragma unroll
    for (int i = 0; i < 16; ++i) {
      const int row = r0 + i * 16;
      const uint4 val = *(const uint4*)(sm + row * 256 + ((cc ^ (row & 7)) * 8));
      const int grow = rowBase + row; // = b*4096 + s, s = l*16+h
      const int b = grow >> 12;
      const int s = grow & 4095;
      const int orow = ((b << 4) + (s & 15)) * 256 + (s >> 4); // (b*16+h)*256 + l
      *(uint4*)(Cb + (long)orow * 1024 + colBase + cc * 8) = val;
    }
  }
#undef STAGE
#undef LDA4
#undef LDB2
#undef MMQ
#undef PH_OPEN
#undef PH_CLOSE
}

extern "C" void kernel_launch(void* const* d_in, const int* in_sizes, int n_in,
                              void* d_out, int out_size, void* d_ws, size_t ws_size,
                              hipStream_t stream) {
  const float* q = (const float*)d_in[0];
  const float* k = (const float*)d_in[1];
  const float* v = (const float*)d_in[2];
  const int* mask = (const int*)d_in[3];
  const float* Wq = (const float*)d_in[4];
  const float* Wk = (const float*)d_in[5];
  const float* Wv = (const float*)d_in[6];
  const float* Wo = (const float*)d_in[7];
  float* out = (float*)d_out;

  char* ws = (char*)d_ws;
  const size_t MB = 1024 * 1024;
  ushort_t* WT = (ushort_t*)ws; // packed [4][1024][1024] bf16: Wq,Wk,Wv,Wo (8MB)
  const dim3 tb(32, 8);
  transpose_w4<<<dim3(32, 32, 4), tb, 0, stream>>>(Wq, Wk, Wv, Wo, WT);

  const bool big = ws_size >= (size_t)200 * MB;

  if (big) {
    // layout: WT 0..8 | qkvb 8..104 | qh 104..136 | kh 136..168 | vh 168..200
    // after proj (qkvb dead): vhT 8..40 | att 40..48 | x 48..80
    ushort_t* qkvb = (ushort_t*)(ws + 8 * MB);
    ushort_t* qh = (ushort_t*)(ws + 104 * MB);
    ushort_t* kh = (ushort_t*)(ws + 136 * MB);
    ushort_t* vh = (ushort_t*)(ws + 168 * MB);
    ushort_t* vhT = (ushort_t*)(ws + 8 * MB);
    ushort_t* att = (ushort_t*)(ws + 40 * MB);
    ushort_t* x = (ushort_t*)(ws + 48 * MB);

    cvt3<<<dim3(8192, 3), 256, 0, stream>>>((const float4*)q, (const float4*)k,
                                            (const float4*)v, (uint4*)qkvb);
    // one batched dispatch: z=0/1/2 -> qh/kh/vh
    gemm256<1><<<768, 512, 0, stream>>>(qkvb, qkvb + (size_t)16777216,
                                        qkvb + (size_t)33554432, WT, qh, 1 << 20,
                                        (long)16777216);
    transpose_v<<<dim3(32, 8, BHN), tb, 0, stream>>>(vh, vhT);
    score_sm<<<256, 256, 0, stream>>>(qh, kh, mask, att);
    gemm_tn<2><<<dim3(8, 2, BHN), 256, 0, stream>>>(att, vhT, x, 256, 256, 256, 1024,
                                                    (long)65536, (long)262144, 0);
    gemm256<0><<<256, 512, 0, stream>>>(x, x, x, WT + (size_t)3145728, out, 0, 0);
  } else {
    // serial fallback (peak 168MB): WT 0..8 | qb 8..40 | qh 40..72 | kh 72..104
    // | vh 104..136 | vhT 136..168 ; after proj: att 8..16 | x 16..48 (qh dead at PV)
    ushort_t* qb = (ushort_t*)(ws + 8 * MB);
    ushort_t* qh = (ushort_t*)(ws + 40 * MB);
    ushort_t* kh = (ushort_t*)(ws + 72 * MB);
    ushort_t* vh = (ushort_t*)(ws + 104 * MB);
    ushort_t* vhT = (ushort_t*)(ws + 136 * MB);
    ushort_t* att = (ushort_t*)(ws + 8 * MB);
    ushort_t* x = (ushort_t*)(ws + 16 * MB);

    cvt3<<<dim3(8192, 1), 256, 0, stream>>>((const float4*)q, (const float4*)q,
                                            (const float4*)q, (uint4*)qb);
    gemm256<1><<<256, 512, 0, stream>>>(qb, qb, qb, WT, qh, 0, 0);
    cvt3<<<dim3(8192, 1), 256, 0, stream>>>((const float4*)k, (const float4*)k,
                                            (const float4*)k, (uint4*)qb);
    gemm256<1><<<256, 512, 0, stream>>>(qb, qb, qb, WT + (size_t)1048576, kh, 0, 0);
    cvt3<<<dim3(8192, 1), 256, 0, stream>>>((const float4*)v, (const float4*)v,
                                            (const float4*)v, (uint4*)qb);
    gemm256<1><<<256, 512, 0, stream>>>(qb, qb, qb, WT + (size_t)2097152, vh, 0, 0);
    transpose_v<<<dim3(32, 8, BHN), tb, 0, stream>>>(vh, vhT);
    score_sm<<<256, 256, 0, stream>>>(qh, kh, mask, att);
    gemm_tn<2><<<dim3(8, 2, BHN), 256, 0, stream>>>(att, vhT, x, 256, 256, 256, 1024,
                                                    (long)65536, (long)262144, 0);
    gemm256<0><<<256, 512, 0, stream>>>(x, x, x, WT + (size_t)3145728, out, 0, 0);
  }
}